// Round 7
// baseline (1315.834 us; speedup 1.0000x reference)
//
#include <hip/hip_runtime.h>
#include <hip/hip_bf16.h>

// HunyuanTopKGate: x[4096,4096] fp32, wg[64,4096] fp32 ->
//   combine_weights [T,E,C] fp32 ++ dispatch_mask [T,E,C] (as fp32 0/1)
// C = out_size/(2*T*E) = 2268 measured -> 4.76 GB output zero-fill (~760us
// at the 6.3 TB/s ceiling) is the roofline pole; everything else must hide
// under it or be tiny.
//
// Round 7: round 6 proved the fill+gemm fusion hides the GEMM (fused kernel
// absent from top-5 => <755us) but verify tripped AGAIN (~500us repair tail)
// even on the audited 4x4 vector GEMM. Can't distinguish "gemm-B bug" from
// "verify always trips" remotely, so: (a) gemm inside the fused kernel is
// now round-1's PROVEN kernel verbatim (passed end-to-end with no repair,
// 550us solo < 750us fill => free when fused); (b) repair rewritten with
// ILP-8 accumulators + float4 loads (old: one dependent fma_f64 chain,
// latency-bound ~500us; new: L2-bound ~150us). Worst case is now cheap.
// dur_us diagnoses the branch: ~820 clean vs ~970 repair-ran.
//
// ws layout: logits[4096][64] double (2MB) | idx_kt | rank_kt | w_kt | flag

#define TOK 4096
#define HID 4096
#define NE  64
#define NK  8
#define GEMMB 256
#define FILLB 2048

// ---------------- 1. fused: proven fp64 GEMM + output zero-fill ----------
// blocks [0,GEMMB): round-1 gemm verbatim -- 16 tokens x 64 experts per
//   block, full-K, thread = (tok=tid&15) x (4 experts at (tid>>4)*4),
//   fp64 fma chains, LDS f32 tiles (xs 16x68, wsh 64x68; +4 pad).
// blocks [GEMMB, GEMMB+FILLB): grid-stride float4 zero of d_out.
// Fill is HBM-write-bound (VALUBusy ~5%), gemm is VALU-bound -> co-schedule
// (m114); gemm hides under the 750us fill.
__global__ __launch_bounds__(256) void fused_gemm_fill(
    const float* __restrict__ x, const float* __restrict__ wg,
    double* __restrict__ logits, float* __restrict__ out, size_t n4,
    int* __restrict__ flag) {
  __shared__ float xs[16][68];
  __shared__ float wsh[64][68];
  const int tid = threadIdx.x;

  if ((int)blockIdx.x >= GEMMB) {
    // ---------------- fill ----------------
    const int fb = (int)blockIdx.x - GEMMB;
    const float4 z4 = make_float4(0.f, 0.f, 0.f, 0.f);
    float4* o4 = (float4*)out;
    for (size_t i = (size_t)fb * 256 + tid; i < n4; i += (size_t)FILLB * 256)
      o4[i] = z4;
    return;
  }

  // ---------------- gemm (round-1 proven structure, verbatim) ----------
  if (blockIdx.x == 0 && tid == 0) *flag = 0;   // clear verify flag
  const int t0  = blockIdx.x * 16;
  const int tok = tid & 15;
  const int eg  = tid >> 4;          // experts eg*4..eg*4+3
  const int lrow = tid >> 4;
  const int lq   = tid & 15;
  double acc[4] = {0.0, 0.0, 0.0, 0.0};

  for (int k0 = 0; k0 < HID; k0 += 64) {
    {
      float4 v = *(const float4*)&x[(size_t)(t0 + lrow) * HID + k0 + lq * 4];
      *(float4*)&xs[lrow][lq * 4] = v;
    }
#pragma unroll
    for (int it = 0; it < 4; ++it) {
      int r = it * 16 + lrow;
      float4 v = *(const float4*)&wg[(size_t)r * HID + k0 + lq * 4];
      *(float4*)&wsh[r][lq * 4] = v;
    }
    __syncthreads();
#pragma unroll
    for (int kk = 0; kk < 64; kk += 4) {
      float4 xv = *(const float4*)&xs[tok][kk];
#pragma unroll
      for (int j = 0; j < 4; ++j) {
        float4 wv = *(const float4*)&wsh[eg * 4 + j][kk];
        acc[j] = fma((double)xv.x, (double)wv.x, acc[j]);
        acc[j] = fma((double)xv.y, (double)wv.y, acc[j]);
        acc[j] = fma((double)xv.z, (double)wv.z, acc[j]);
        acc[j] = fma((double)xv.w, (double)wv.w, acc[j]);
      }
    }
    __syncthreads();
  }
#pragma unroll
  for (int j = 0; j < 4; ++j)
    logits[(size_t)(t0 + tok) * NE + eg * 4 + j] = acc[j];
}

// ---------------- 1b. verify: sample 512 logits vs exact fp64 dots --------
__global__ __launch_bounds__(256) void verify_kernel(
    const float* __restrict__ x, const float* __restrict__ wg,
    const double* __restrict__ logits, int* __restrict__ flag) {
  const int gid  = blockIdx.x * blockDim.x + threadIdx.x;
  const int wid  = gid >> 6;          // 0..511
  const int lane = gid & 63;
  const int t = (wid * 521) & (TOK - 1);
  const int e = wid & 63;
  double acc = 0.0;
  for (int k = lane; k < HID; k += 64)
    acc = fma((double)x[(size_t)t * HID + k], (double)wg[(size_t)e * HID + k], acc);
#pragma unroll
  for (int off = 32; off; off >>= 1) acc += __shfl_xor(acc, off);
  if (lane == 0) {
    double got = logits[(size_t)t * NE + e];
    if (!(fabs(got - acc) <= 1e-6)) atomicOr(flag, 1);  // NaN-safe
  }
}

// ---------------- 1c. repair: ILP-8 fp64 recompute if flag set -----------
// 8 independent accumulators break the fma_f64 latency chain; float4 loads.
// x row broadcasts across the wave (e = lane); wg streams from L2 (~4 GB
// aggregate -> ~150us). Contingency path only.
__global__ __launch_bounds__(256) void repair_gemm(
    const float* __restrict__ x, const float* __restrict__ wg,
    double* __restrict__ logits, const int* __restrict__ flag) {
  if (*(volatile const int*)flag == 0) return;
  const int gid = blockIdx.x * 256 + threadIdx.x;   // 0..262143
  const int t = gid >> 6;
  const int e = gid & 63;
  double a0 = 0, a1 = 0, a2 = 0, a3 = 0, a4 = 0, a5 = 0, a6 = 0, a7 = 0;
  const float* xr = x  + (size_t)t * HID;
  const float* wr = wg + (size_t)e * HID;
  for (int k = 0; k < HID; k += 8) {
    float4 xv0 = *(const float4*)&xr[k];
    float4 xv1 = *(const float4*)&xr[k + 4];
    float4 wv0 = *(const float4*)&wr[k];
    float4 wv1 = *(const float4*)&wr[k + 4];
    a0 = fma((double)xv0.x, (double)wv0.x, a0);
    a1 = fma((double)xv0.y, (double)wv0.y, a1);
    a2 = fma((double)xv0.z, (double)wv0.z, a2);
    a3 = fma((double)xv0.w, (double)wv0.w, a3);
    a4 = fma((double)xv1.x, (double)wv1.x, a4);
    a5 = fma((double)xv1.y, (double)wv1.y, a5);
    a6 = fma((double)xv1.z, (double)wv1.z, a6);
    a7 = fma((double)xv1.w, (double)wv1.w, a7);
  }
  logits[(size_t)t * NE + e] = ((((((a0 + a1) + a2) + a3) + a4) + a5) + a6) + a7;
}

// ---------------- 2. softmax + top-8 per token (one wave64/token) ----------
__global__ __launch_bounds__(256) void topk_kernel(
    const double* __restrict__ logits,
    int* __restrict__ idx_kt, float* __restrict__ w_kt) {
  const int gid  = blockIdx.x * blockDim.x + threadIdx.x;
  const int t    = gid >> 6;
  const int lane = gid & 63;

  double v = logits[(size_t)t * NE + lane];

  double m = v;
#pragma unroll
  for (int off = 32; off; off >>= 1) {
    double o = __shfl_xor(m, off);
    m = o > m ? o : m;
  }
  double g = exp(v - m);
  double s = g;
#pragma unroll
  for (int off = 32; off; off >>= 1) s += __shfl_xor(s, off);
  double gate = g / s;

  float key = (float)gate;    // fp32-rounded selection key, tie -> lower idx
  double ssel = 0.0;
  int my_k = -1;
#pragma unroll
  for (int k = 0; k < NK; ++k) {
    float bv = key;
    int   bi = lane;
#pragma unroll
    for (int off = 32; off; off >>= 1) {
      float ov = __shfl_xor(bv, off);
      int   oi = __shfl_xor(bi, off);
      if (ov > bv || (ov == bv && oi < bi)) { bv = ov; bi = oi; }
    }
    ssel += __shfl(gate, bi);
    if (lane == bi) { my_k = k; key = -1.0f; }
  }
  double gs = ssel;
  const double eps = (double)1.1920929e-07f;
  if (gs < eps) gs = eps;

  if (my_k >= 0) {
    idx_kt[my_k * TOK + t] = lane;
    w_kt [my_k * TOK + t] = (float)(gate / gs);
  }
}

// ---------------- 3. ranks: stable prefix count per expert --------------
__global__ __launch_bounds__(1024) void rank_kernel(
    const int* __restrict__ idx_kt, int* __restrict__ rank_kt) {
  const int e    = blockIdx.x;
  const int tid  = threadIdx.x;
  const int lane = tid & 63;
  const int w    = tid >> 6;          // 0..15
  __shared__ int wt[16];
  int running = 0;
  const unsigned long long below = (1ull << lane) - 1ull;

  for (int i0 = 0; i0 < NK * TOK; i0 += 1024) {
    const int i = i0 + tid;
    const bool mhit = (idx_kt[i] == e);
    unsigned long long mask = __ballot(mhit);
    if (lane == 0) wt[w] = __popcll(mask);
    __syncthreads();
    int woff = 0, tot = 0;
#pragma unroll
    for (int j = 0; j < 16; ++j) {
      int c = wt[j];
      tot += c;
      if (j < w) woff += c;
    }
    if (mhit) rank_kt[i] = running + woff + __popcll(mask & below);
    running += tot;
    __syncthreads();
  }
}

// ---------------- 4. scatter the 32768 nonzeros ----------------
__global__ __launch_bounds__(256) void scatter_kernel(
    const int* __restrict__ idx_kt, const int* __restrict__ rank_kt,
    const float* __restrict__ w_kt, float* __restrict__ out, int C) {
  const int i = blockIdx.x * 256 + threadIdx.x;   // 0..32767, = k*TOK + t
  const int t = i & (TOK - 1);
  const int e = idx_kt[i];
  const int c = rank_kt[i];
  const float wv = w_kt[i];
  if (e >= 0 && e < NE && c >= 0 && c < C) {
    size_t off = ((size_t)t * NE + e) * (size_t)C + (size_t)c;
    out[off] = wv;                                // combine_weights
    out[(size_t)TOK * NE * C + off] = 1.0f;       // dispatch_mask
  }
}

extern "C" void kernel_launch(void* const* d_in, const int* in_sizes, int n_in,
                              void* d_out, int out_size, void* d_ws, size_t ws_size,
                              hipStream_t stream) {
  const float* x  = (const float*)d_in[0];   // [4096,4096]
  const float* wg = (const float*)d_in[1];   // [64,4096]
  float* out = (float*)d_out;

  const int C = out_size / (2 * TOK * NE);   // capacity from output size

  char* ws = (char*)d_ws;
  double* logits  = (double*)ws;                                   // 2 MB
  int*    idx_kt  = (int*)  (ws + (size_t)2 * 1024 * 1024);
  int*    rank_kt = (int*)  (ws + (size_t)2 * 1024 * 1024 + (size_t)NK * TOK * 4);
  float*  w_kt    = (float*)(ws + (size_t)2 * 1024 * 1024 + (size_t)NK * TOK * 8);
  int*    flag    = (int*)  (ws + (size_t)2 * 1024 * 1024 + (size_t)NK * TOK * 12);

  const size_t n4 = (size_t)out_size >> 2;   // out_size divisible by 4

  // one dispatch: gemm blocks first (start immediately), fill blocks behind
  fused_gemm_fill<<<GEMMB + FILLB, 256, 0, stream>>>(x, wg, logits, out, n4, flag);
  verify_kernel  <<<128, 256, 0, stream>>>(x, wg, logits, flag);
  repair_gemm    <<<TOK * NE / 256, 256, 0, stream>>>(x, wg, logits, flag);
  topk_kernel    <<<TOK * 64 / 256, 256, 0, stream>>>(logits, idx_kt, w_kt);
  rank_kernel    <<<NE, 1024, 0, stream>>>(idx_kt, rank_kt);
  scatter_kernel <<<NK * TOK / 256, 256, 0, stream>>>(idx_kt, rank_kt, w_kt, out, C);
}

// Round 8
// 1291.094 us; speedup vs baseline: 1.0192x; 1.0192x over previous
//
#include <hip/hip_runtime.h>
#include <hip/hip_bf16.h>

// HunyuanTopKGate: x[4096,4096] fp32, wg[64,4096] fp32 ->
//   combine_weights [T,E,C] fp32 ++ dispatch_mask [T,E,C] (as fp32 0/1)
// C = out_size/(2*T*E) = 2268 measured -> 4.76 GB output zero-fill (~760us
// at the 6.3 TB/s ceiling) is the roofline pole.
//
// Round 8: DELETE verify+repair. Evidence: verify tripped in rounds 3/5/6/7,
// including round 7 where the gemm was round-1's kernel VERBATIM (which
// passed end-to-end standalone in round 1, absmax 4.9e-4, before any repair
// path existed). The gemm and fill touch disjoint buffers; topk uses the
// same __shfl_xor-double reduction and works; fp64 accum error ~1e-14 vs
// 1e-6 tolerance. All observations fit "verify/flag path broken", none fit
// "three independent GEMMs all wrong". Round-7 tail arithmetic: 1316-760 =
// 556us = verify(5)+repair(~500: 8GB L3-bound, not 150 as estimated)+45.
// This round is the discriminating experiment AND the win: PASS => ~810us
// (output-write roofline); FAIL => fused-context corruption is real, revert.
//
// ws layout: logits[4096][64] double (2MB) | idx_kt | rank_kt | w_kt

#define TOK 4096
#define HID 4096
#define NE  64
#define NK  8
#define GEMMB 256
#define FILLB 2048

// ---------------- 1. fused: proven fp64 GEMM + output zero-fill ----------
// blocks [0,GEMMB): round-1 gemm verbatim -- 16 tokens x 64 experts per
//   block, full-K, thread = (tok=tid&15) x (4 experts at (tid>>4)*4),
//   fp64 fma chains, LDS f32 tiles (xs 16x68, wsh 64x68).  ~550us solo.
// blocks [GEMMB, GEMMB+FILLB): grid-stride float4 zero of d_out. ~760us.
// Gemm is VALU/latency-bound, fill is HBM-write-bound -> co-resident waves
// overlap (m114); gemm hides under the fill (round 6/7: fused kernel never
// exceeded the ~760us poison fills in the profile).
__global__ __launch_bounds__(256) void fused_gemm_fill(
    const float* __restrict__ x, const float* __restrict__ wg,
    double* __restrict__ logits, float* __restrict__ out, size_t n4) {
  __shared__ float xs[16][68];
  __shared__ float wsh[64][68];
  const int tid = threadIdx.x;

  if ((int)blockIdx.x >= GEMMB) {
    // ---------------- fill ----------------
    const int fb = (int)blockIdx.x - GEMMB;
    const float4 z4 = make_float4(0.f, 0.f, 0.f, 0.f);
    float4* o4 = (float4*)out;
    for (size_t i = (size_t)fb * 256 + tid; i < n4; i += (size_t)FILLB * 256)
      o4[i] = z4;
    return;
  }

  // ---------------- gemm (round-1 proven structure, verbatim) ----------
  const int t0  = blockIdx.x * 16;
  const int tok = tid & 15;
  const int eg  = tid >> 4;          // experts eg*4..eg*4+3
  const int lrow = tid >> 4;
  const int lq   = tid & 15;
  double acc[4] = {0.0, 0.0, 0.0, 0.0};

  for (int k0 = 0; k0 < HID; k0 += 64) {
    {
      float4 v = *(const float4*)&x[(size_t)(t0 + lrow) * HID + k0 + lq * 4];
      *(float4*)&xs[lrow][lq * 4] = v;
    }
#pragma unroll
    for (int it = 0; it < 4; ++it) {
      int r = it * 16 + lrow;
      float4 v = *(const float4*)&wg[(size_t)r * HID + k0 + lq * 4];
      *(float4*)&wsh[r][lq * 4] = v;
    }
    __syncthreads();
#pragma unroll
    for (int kk = 0; kk < 64; kk += 4) {
      float4 xv = *(const float4*)&xs[tok][kk];
#pragma unroll
      for (int j = 0; j < 4; ++j) {
        float4 wv = *(const float4*)&wsh[eg * 4 + j][kk];
        acc[j] = fma((double)xv.x, (double)wv.x, acc[j]);
        acc[j] = fma((double)xv.y, (double)wv.y, acc[j]);
        acc[j] = fma((double)xv.z, (double)wv.z, acc[j]);
        acc[j] = fma((double)xv.w, (double)wv.w, acc[j]);
      }
    }
    __syncthreads();
  }
#pragma unroll
  for (int j = 0; j < 4; ++j)
    logits[(size_t)(t0 + tok) * NE + eg * 4 + j] = acc[j];
}

// ---------------- 2. softmax + top-8 per token (one wave64/token) ----------
// fp64 softmax; selection key = fp32-rounded gate, tie -> lower index
// (mimics jax.lax.top_k on fp32 gates). Proven rounds 1-7.
__global__ __launch_bounds__(256) void topk_kernel(
    const double* __restrict__ logits,
    int* __restrict__ idx_kt, float* __restrict__ w_kt) {
  const int gid  = blockIdx.x * blockDim.x + threadIdx.x;
  const int t    = gid >> 6;
  const int lane = gid & 63;

  double v = logits[(size_t)t * NE + lane];

  double m = v;
#pragma unroll
  for (int off = 32; off; off >>= 1) {
    double o = __shfl_xor(m, off);
    m = o > m ? o : m;
  }
  double g = exp(v - m);
  double s = g;
#pragma unroll
  for (int off = 32; off; off >>= 1) s += __shfl_xor(s, off);
  double gate = g / s;

  float key = (float)gate;
  double ssel = 0.0;
  int my_k = -1;
#pragma unroll
  for (int k = 0; k < NK; ++k) {
    float bv = key;
    int   bi = lane;
#pragma unroll
    for (int off = 32; off; off >>= 1) {
      float ov = __shfl_xor(bv, off);
      int   oi = __shfl_xor(bi, off);
      if (ov > bv || (ov == bv && oi < bi)) { bv = ov; bi = oi; }
    }
    ssel += __shfl(gate, bi);
    if (lane == bi) { my_k = k; key = -1.0f; }
  }
  double gs = ssel;
  const double eps = (double)1.1920929e-07f;
  if (gs < eps) gs = eps;

  if (my_k >= 0) {
    idx_kt[my_k * TOK + t] = lane;
    w_kt [my_k * TOK + t] = (float)(gate / gs);
  }
}

// ---------------- 3. ranks: stable prefix count per expert --------------
__global__ __launch_bounds__(1024) void rank_kernel(
    const int* __restrict__ idx_kt, int* __restrict__ rank_kt) {
  const int e    = blockIdx.x;
  const int tid  = threadIdx.x;
  const int lane = tid & 63;
  const int w    = tid >> 6;          // 0..15
  __shared__ int wt[16];
  int running = 0;
  const unsigned long long below = (1ull << lane) - 1ull;

  for (int i0 = 0; i0 < NK * TOK; i0 += 1024) {
    const int i = i0 + tid;
    const bool mhit = (idx_kt[i] == e);
    unsigned long long mask = __ballot(mhit);
    if (lane == 0) wt[w] = __popcll(mask);
    __syncthreads();
    int woff = 0, tot = 0;
#pragma unroll
    for (int j = 0; j < 16; ++j) {
      int c = wt[j];
      tot += c;
      if (j < w) woff += c;
    }
    if (mhit) rank_kt[i] = running + woff + __popcll(mask & below);
    running += tot;
    __syncthreads();
  }
}

// ---------------- 4. scatter the 32768 nonzeros ----------------
__global__ __launch_bounds__(256) void scatter_kernel(
    const int* __restrict__ idx_kt, const int* __restrict__ rank_kt,
    const float* __restrict__ w_kt, float* __restrict__ out, int C) {
  const int i = blockIdx.x * 256 + threadIdx.x;   // 0..32767, = k*TOK + t
  const int t = i & (TOK - 1);
  const int e = idx_kt[i];
  const int c = rank_kt[i];
  const float wv = w_kt[i];
  if (e >= 0 && e < NE && c >= 0 && c < C) {
    size_t off = ((size_t)t * NE + e) * (size_t)C + (size_t)c;
    out[off] = wv;                                // combine_weights
    out[(size_t)TOK * NE * C + off] = 1.0f;       // dispatch_mask
  }
}

extern "C" void kernel_launch(void* const* d_in, const int* in_sizes, int n_in,
                              void* d_out, int out_size, void* d_ws, size_t ws_size,
                              hipStream_t stream) {
  const float* x  = (const float*)d_in[0];   // [4096,4096]
  const float* wg = (const float*)d_in[1];   // [64,4096]
  float* out = (float*)d_out;

  const int C = out_size / (2 * TOK * NE);   // capacity from output size

  char* ws = (char*)d_ws;
  double* logits  = (double*)ws;                                   // 2 MB
  int*    idx_kt  = (int*)  (ws + (size_t)2 * 1024 * 1024);
  int*    rank_kt = (int*)  (ws + (size_t)2 * 1024 * 1024 + (size_t)NK * TOK * 4);
  float*  w_kt    = (float*)(ws + (size_t)2 * 1024 * 1024 + (size_t)NK * TOK * 8);

  const size_t n4 = (size_t)out_size >> 2;   // out_size = 2*T*E*C, /4 exact

  // one dispatch: gemm blocks first (start immediately), fill blocks behind
  fused_gemm_fill<<<GEMMB + FILLB, 256, 0, stream>>>(x, wg, logits, out, n4);
  topk_kernel    <<<TOK * 64 / 256, 256, 0, stream>>>(logits, idx_kt, w_kt);
  rank_kernel    <<<NE, 1024, 0, stream>>>(idx_kt, rank_kt);
  scatter_kernel <<<NK * TOK / 256, 256, 0, stream>>>(idx_kt, rank_kt, w_kt, out, C);
}